// Round 12
// baseline (272.414 us; speedup 1.0000x reference)
//
#include <hip/hip_runtime.h>

#define MU 256
#define NPIX (MU*MU)
#define ML 3
#define KS 7
#define LCH 7
#define NENT 35   // 28 upper-tri M entries + 7 b entries
#define RBLK 64   // partial blocks per sample (grid 4x16)

// ---------------- MLP: per-sample dynamic kernels ----------------
__global__ void mlp_kernel(const float* __restrict__ kernelA,
                           const float* __restrict__ fc1_w1, const float* __restrict__ fc1_b1,
                           const float* __restrict__ fc1_w2, const float* __restrict__ fc1_b2,
                           const float* __restrict__ fc2_w1, const float* __restrict__ fc2_b1,
                           const float* __restrict__ fc2_w2, const float* __restrict__ fc2_b2,
                           float* __restrict__ w1_out, float* __restrict__ w2_out) {
    int b = blockIdx.x;
    int t = threadIdx.x;
    __shared__ float kA[9];
    __shared__ float h1[200], h2[200];
    if (t < 9) kA[t] = kernelA[b*9 + t];
    __syncthreads();
    if (t < 200) {
        float s1 = fc1_b1[t], s2 = fc2_b1[t];
        #pragma unroll
        for (int i = 0; i < 9; ++i) {
            s1 += kA[i] * fc1_w1[i*200 + t];
            s2 += kA[i] * fc2_w1[i*200 + t];
        }
        h1[t] = fmaxf(s1, 0.f);
        h2[t] = fmaxf(s2, 0.f);
    }
    __syncthreads();
    if (t < 147) {
        float s = fc1_b2[t];
        for (int i = 0; i < 200; ++i) s += h1[i] * fc1_w2[i*147 + t];
        w1_out[b*147 + t] = s;
    }
    for (int o = t; o < 441; o += 256) {
        float s = fc2_b2[o];
        for (int i = 0; i < 200; ++i) s += h2[i] * fc2_w2[i*441 + o];
        w2_out[b*441 + o] = s;
    }
}

// ---- r = f - conv3x3(x, kernelA). Block (64,4), float4-staged LDS tile. ----
__global__ __launch_bounds__(256, 4) void residual_kernel(
        const float* __restrict__ x, const float* __restrict__ f,
        const float* __restrict__ kA, float* __restrict__ r) {
    int b = blockIdx.z;
    __shared__ float tile[18][72];
    int tx = threadIdx.x, ty = threadIdx.y;
    int tid = ty*64 + tx;
    float k[9];
    #pragma unroll
    for (int i = 0; i < 9; ++i) k[i] = kA[b*9 + i];
    int x0 = blockIdx.x*64, ysub = blockIdx.y*16;
    const float* xb = x + (size_t)b*NPIX;

    for (int u = tid; u < 18*18; u += 256) {
        int row = u / 18, q4 = u % 18;
        int yy = ysub + row - 1;
        int xx = x0 - 4 + q4*4;
        float4 vv = make_float4(0.f, 0.f, 0.f, 0.f);
        if (yy >= 0 && yy < MU && xx >= 0 && xx < MU)
            vv = *(const float4*)(xb + yy*MU + xx);
        *(float4*)&tile[row][q4*4] = vv;
    }
    __syncthreads();

    int ry = ty*4;
    float S0 = 0.f, S1 = 0.f, S2 = 0.f, S3 = 0.f;
    #pragma unroll
    for (int t = 0; t < 6; ++t) {
        float v0 = tile[ry + t][tx + 3];
        float v1 = tile[ry + t][tx + 4];
        float v2 = tile[ry + t][tx + 5];
        float e0 = v0*k[0] + v1*k[1] + v2*k[2];
        float e1 = v0*k[3] + v1*k[4] + v2*k[5];
        float e2 = v0*k[6] + v1*k[7] + v2*k[8];
        if (t == 0) { S0 += e0; }
        if (t == 1) { S1 += e0; S0 += e1; }
        if (t == 2) { S2 += e0; S1 += e1; S0 += e2; }
        if (t == 3) { S3 += e0; S2 += e1; S1 += e2; }
        if (t == 4) {           S3 += e1; S2 += e2; }
        if (t == 5) {                     S3 += e2; }
    }
    float Sv[4] = {S0, S1, S2, S3};
    #pragma unroll
    for (int dy = 0; dy < 4; ++dy) {
        size_t p = (size_t)b*NPIX + (size_t)(ysub + ry + dy)*MU + x0 + tx;
        r[p] = f[p] - Sv[dy];
    }
}

// ---- conv7x7 1->3ch. Block (64,4), 2 cols x 4 rows per thread (8 px),
//      tile[22][136] staged as float4, b64 LDS reads, SGPR weights. ----
__global__ __launch_bounds__(256) void conv7_g1(
        const float* __restrict__ r, const float* __restrict__ w1,
        float* __restrict__ G1) {
    int b = blockIdx.z;
    __shared__ float tile[22][136];
    int tx = threadIdx.x;
    int ty = threadIdx.y;
    int tid = ty*64 + tx;
    int x0 = blockIdx.x*128, y0 = blockIdx.y*16;
    const float* rb = r + (size_t)b*NPIX;
    const float* wgt = w1 + (size_t)b*147;

    for (int u = tid; u < 22*34; u += 256) {
        int row = u / 34, q4 = u % 34;
        int yy = y0 + row - 3;
        int xx = x0 - 4 + q4*4;
        float4 vv = make_float4(0.f, 0.f, 0.f, 0.f);
        if (yy >= 0 && yy < MU && xx >= 0 && xx < MU)
            vv = *(const float4*)(rb + yy*MU + xx);
        *(float4*)&tile[row][q4*4] = vv;
    }
    __syncthreads();

    float accA[3][4], accB[3][4];
    #pragma unroll
    for (int co = 0; co < 3; ++co)
        #pragma unroll
        for (int dy = 0; dy < 4; ++dy) { accA[co][dy] = 0.f; accB[co][dy] = 0.f; }

    int ry = ty*4;
    #pragma unroll
    for (int ir = 0; ir < 10; ++ir) {
        float v[10];
        #pragma unroll
        for (int h = 0; h < 5; ++h)
            *(float2*)&v[h*2] = *(float2*)&tile[ry + ir][2*tx + h*2];
        #pragma unroll
        for (int dy = 0; dy < 4; ++dy) {
            int i = ir - dy;
            if (i >= 0 && i <= 6) {
                #pragma unroll
                for (int co = 0; co < 3; ++co)
                    #pragma unroll
                    for (int j = 0; j < 7; ++j) {
                        float w = wgt[(co*7 + i)*7 + j];
                        accA[co][dy] += v[1 + j] * w;
                        accB[co][dy] += v[2 + j] * w;
                    }
            }
        }
    }
    #pragma unroll
    for (int dy = 0; dy < 4; ++dy) {
        size_t p = (size_t)b*3*NPIX + (size_t)(y0 + ry + dy)*MU + x0 + 2*tx;
        #pragma unroll
        for (int co = 0; co < 3; ++co)
            *(float2*)&G1[p + (size_t)co*NPIX] = make_float2(accA[co][dy], accB[co][dy]);
    }
}

// ---- FUSED conv7x7 3->3ch + S=depthwise3x3 + Gram partials.
//      Block (64,4), output region 64x16. Computes G2 on expanded
//      68x18 region into LDS (halo +-1 for the S stencil), writes the
//      interior 64x16 to global, then computes S for all 7 channels and
//      the 35 Gram entries with the butterfly split-reduce. Replaces the
//      separate conv7_g2 + reduce_kernel (saves the 117 MB restage). ----
__global__ __launch_bounds__(256) void g2gram_kernel(
        const float* __restrict__ G1, const float* __restrict__ r,
        const float* __restrict__ w2, const float* __restrict__ kA,
        float* __restrict__ G2, float* __restrict__ partial) {
    int b = blockIdx.z;
    __shared__ float g1t[3][24][80];   // rows y0-4..y0+19, cols x0-8..x0+71
    __shared__ float g2t[3][18][68];   // rows y0-1..y0+16, cols x0-2..x0+65
    __shared__ float rt[18][72];       // rows y0-1..y0+16, cols x0-4..x0+67
    __shared__ float wsum[NENT][4];
    int tx = threadIdx.x;              // 0..63 = lane; wave == one ty
    int ty = threadIdx.y;              // 0..3
    int tid = ty*64 + tx;
    int x0 = blockIdx.x*64, y0 = blockIdx.y*16;
    const float* g1b = G1 + (size_t)b*3*NPIX;
    const float* rb  = r  + (size_t)b*NPIX;
    const float* wgt = w2 + (size_t)b*441;   // uniform -> SGPR loads
    float k[9];
    #pragma unroll
    for (int i = 0; i < 9; ++i) k[i] = kA[b*9 + i];

    // ---- phase 1: stage G1 + r ----
    for (int u = tid; u < 3*24*20; u += 256) {
        int c = u / (24*20);
        int rem = u % (24*20);
        int row = rem / 20, q4 = rem % 20;
        int yy = y0 + row - 4;
        int xx = x0 - 8 + q4*4;
        float4 vv = make_float4(0.f, 0.f, 0.f, 0.f);
        if (yy >= 0 && yy < MU && xx >= 0 && xx < MU)
            vv = *(const float4*)(g1b + (size_t)c*NPIX + yy*MU + xx);
        *(float4*)&g1t[c][row][q4*4] = vv;
    }
    for (int u = tid; u < 18*18; u += 256) {
        int row = u / 18, q4 = u % 18;
        int yy = y0 + row - 1;
        int xx = x0 - 4 + q4*4;
        float4 vv = make_float4(0.f, 0.f, 0.f, 0.f);
        if (yy >= 0 && yy < MU && xx >= 0 && xx < MU)
            vv = *(const float4*)(rb + yy*MU + xx);
        *(float4*)&rt[row][q4*4] = vv;
    }
    __syncthreads();

    // ---- phase 2: expanded G2 (18 rows x 34 col-pairs = 612 tasks) ----
    for (int t = tid; t < 18*34; t += 256) {
        int row = t / 34, p = t % 34;   // image y = y0-1+row, x = x0-2+2p (+1)
        float accA[3] = {0.f, 0.f, 0.f}, accB[3] = {0.f, 0.f, 0.f};
        #pragma unroll
        for (int c = 0; c < 3; ++c)
            #pragma unroll
            for (int ir = 0; ir < 7; ++ir) {
                float v[10];
                #pragma unroll
                for (int h = 0; h < 5; ++h)
                    *(float2*)&v[2*h] = *(float2*)&g1t[c][row + ir][2*p + 2 + 2*h];
                #pragma unroll
                for (int co = 0; co < 3; ++co)
                    #pragma unroll
                    for (int j = 0; j < 7; ++j) {
                        float w = wgt[((co*3 + c)*7 + ir)*7 + j];
                        accA[co] += v[1 + j] * w;
                        accB[co] += v[2 + j] * w;
                    }
            }
        #pragma unroll
        for (int co = 0; co < 3; ++co)
            *(float2*)&g2t[co][row][2*p] = make_float2(accA[co], accB[co]);
        if (row >= 1 && row <= 16 && p >= 1 && p <= 32) {
            size_t q = (size_t)b*3*NPIX + (size_t)(y0 + row - 1)*MU + (x0 - 2 + 2*p);
            #pragma unroll
            for (int co = 0; co < 3; ++co)
                *(float2*)&G2[q + (size_t)co*NPIX] = make_float2(accA[co], accB[co]);
        }
    }
    __syncthreads();

    // ---- phase 3: S (7 channels) + Gram. px (x0+tx, y0+ry+dy), dy 0..3 ----
    int ry = ty*4;
    float S_all[7][4];
    // c = 0 : r, rt rows ry..ry+5, cols tx+3..tx+5
    {
        float S0 = 0.f, S1 = 0.f, S2 = 0.f, S3 = 0.f;
        #pragma unroll
        for (int t = 0; t < 6; ++t) {
            float v0 = rt[ry + t][tx + 3];
            float v1 = rt[ry + t][tx + 4];
            float v2 = rt[ry + t][tx + 5];
            float e0 = v0*k[0] + v1*k[1] + v2*k[2];
            float e1 = v0*k[3] + v1*k[4] + v2*k[5];
            float e2 = v0*k[6] + v1*k[7] + v2*k[8];
            if (t == 0) { S0 += e0; }
            if (t == 1) { S1 += e0; S0 += e1; }
            if (t == 2) { S2 += e0; S1 += e1; S0 += e2; }
            if (t == 3) { S3 += e0; S2 += e1; S1 += e2; }
            if (t == 4) {           S3 += e1; S2 += e2; }
            if (t == 5) {                     S3 += e2; }
        }
        S_all[0][0] = S0; S_all[0][1] = S1; S_all[0][2] = S2; S_all[0][3] = S3;
    }
    // c = 1..3 : G1, g1t rows ry+3.., cols tx+7..tx+9
    #pragma unroll
    for (int ci = 0; ci < 3; ++ci) {
        float S0 = 0.f, S1 = 0.f, S2 = 0.f, S3 = 0.f;
        #pragma unroll
        for (int t = 0; t < 6; ++t) {
            float v0 = g1t[ci][ry + 3 + t][tx + 7];
            float v1 = g1t[ci][ry + 3 + t][tx + 8];
            float v2 = g1t[ci][ry + 3 + t][tx + 9];
            float e0 = v0*k[0] + v1*k[1] + v2*k[2];
            float e1 = v0*k[3] + v1*k[4] + v2*k[5];
            float e2 = v0*k[6] + v1*k[7] + v2*k[8];
            if (t == 0) { S0 += e0; }
            if (t == 1) { S1 += e0; S0 += e1; }
            if (t == 2) { S2 += e0; S1 += e1; S0 += e2; }
            if (t == 3) { S3 += e0; S2 += e1; S1 += e2; }
            if (t == 4) {           S3 += e1; S2 += e2; }
            if (t == 5) {                     S3 += e2; }
        }
        S_all[1 + ci][0] = S0; S_all[1 + ci][1] = S1;
        S_all[1 + ci][2] = S2; S_all[1 + ci][3] = S3;
    }
    // c = 4..6 : G2, g2t rows ry.., cols tx+1..tx+3
    #pragma unroll
    for (int ci = 0; ci < 3; ++ci) {
        float S0 = 0.f, S1 = 0.f, S2 = 0.f, S3 = 0.f;
        #pragma unroll
        for (int t = 0; t < 6; ++t) {
            float v0 = g2t[ci][ry + t][tx + 1];
            float v1 = g2t[ci][ry + t][tx + 2];
            float v2 = g2t[ci][ry + t][tx + 3];
            float e0 = v0*k[0] + v1*k[1] + v2*k[2];
            float e1 = v0*k[3] + v1*k[4] + v2*k[5];
            float e2 = v0*k[6] + v1*k[7] + v2*k[8];
            if (t == 0) { S0 += e0; }
            if (t == 1) { S1 += e0; S0 += e1; }
            if (t == 2) { S2 += e0; S1 += e1; S0 += e2; }
            if (t == 3) { S3 += e0; S2 += e1; S1 += e2; }
            if (t == 4) {           S3 += e1; S2 += e2; }
            if (t == 5) {                     S3 += e2; }
        }
        S_all[4 + ci][0] = S0; S_all[4 + ci][1] = S1;
        S_all[4 + ci][2] = S2; S_all[4 + ci][3] = S3;
    }

    float acc[64];
    #pragma unroll
    for (int e = 0; e < 64; ++e) acc[e] = 0.f;

    #pragma unroll
    for (int dy = 0; dy < 4; ++dy) {
        float rv = rt[ry + dy + 1][tx + 4];
        int idx = 0;
        #pragma unroll
        for (int l = 0; l < 7; ++l) {
            #pragma unroll
            for (int m = l; m < 7; ++m) {
                acc[idx] += S_all[l][dy] * S_all[m][dy];
                ++idx;
            }
        }
        #pragma unroll
        for (int l = 0; l < 7; ++l) acc[28 + l] += S_all[l][dy] * rv;
    }

    // butterfly split-reduce: lane ends holding full sum of entry bitrev6(lane)
    #pragma unroll
    for (int step = 0; step < 6; ++step) {
        const int mask = 1 << step;
        const int nh = 32 >> step;
        bool hi = (tx & mask) != 0;
        #pragma unroll
        for (int i = 0; i < nh; ++i) {
            float send = hi ? acc[i] : acc[i + nh];
            float got = __shfl_xor(send, mask);
            acc[i] = (hi ? acc[i + nh] : acc[i]) + got;
        }
    }
    int ent = ((tx&1)<<5) | ((tx&2)<<3) | ((tx&4)<<1)
            | ((tx&8)>>1) | ((tx&16)>>3) | ((tx&32)>>5);
    if (ent < NENT) wsum[ent][ty] = acc[0];
    __syncthreads();
    if (tid < NENT) {
        float s = wsum[tid][0] + wsum[tid][1] + wsum[tid][2] + wsum[tid][3];
        int blockLinear = blockIdx.y*4 + blockIdx.x;   // 0..63
        partial[((size_t)b*NENT + tid)*RBLK + blockLinear] = s;
    }
}

// ---- stage-2: sum RBLK per-block partials per (sample, entry) in f64 ----
__global__ void reduce2_kernel(const float* __restrict__ partial,
                               double* __restrict__ M, double* __restrict__ bv) {
    int b = blockIdx.x;
    int wave = threadIdx.x >> 6;
    int lane = threadIdx.x & 63;
    for (int e = wave; e < NENT; e += 4) {
        const float* p = partial + ((size_t)b*NENT + e)*RBLK;
        double s = (double)p[lane];
        #pragma unroll
        for (int off = 32; off; off >>= 1) s += __shfl_down(s, off);
        if (lane == 0) {
            if (e < 28) M[b*28 + e] = s;
            else        bv[b*7 + (e - 28)] = s;
        }
    }
}

// ---- per-sample 7x7 solve: f64, partial pivoting, ALL-STATIC indexing ----
__global__ __launch_bounds__(64, 1) void solve_kernel(
        const double* __restrict__ M, const double* __restrict__ bv,
        float* __restrict__ K, int B) {
    int b = blockIdx.x*64 + threadIdx.x;
    if (b >= B) return;
    double A[7][8];
    int idx = 0;
    #pragma unroll
    for (int l = 0; l < 7; ++l)
        #pragma unroll
        for (int m = l; m < 7; ++m) {
            double v = M[b*28 + idx];
            A[l][m] = v;
            A[m][l] = v;
            ++idx;
        }
    #pragma unroll
    for (int l = 0; l < 7; ++l) A[l][7] = bv[b*7 + l];

    #pragma unroll
    for (int col = 0; col < 7; ++col) {
        int piv = col;
        double mx = fabs(A[col][col]);
        #pragma unroll
        for (int rr = 0; rr < 7; ++rr) {
            if (rr > col) {
                double a = fabs(A[rr][col]);
                if (a > mx) { mx = a; piv = rr; }
            }
        }
        #pragma unroll
        for (int rr = 0; rr < 7; ++rr) {
            if (rr > col) {
                bool c = (rr == piv);
                #pragma unroll
                for (int cc = 0; cc < 8; ++cc) {
                    double t0 = A[col][cc], t1 = A[rr][cc];
                    A[col][cc] = c ? t1 : t0;
                    A[rr][cc]  = c ? t0 : t1;
                }
            }
        }
        double d = A[col][col];
        #pragma unroll
        for (int rr = 0; rr < 7; ++rr) {
            if (rr > col) {
                double fct = A[rr][col] / d;
                #pragma unroll
                for (int cc = 0; cc < 8; ++cc) A[rr][cc] -= fct * A[col][cc];
            }
        }
    }
    double Kv[7];
    #pragma unroll
    for (int rr = 6; rr >= 0; --rr) {
        double s = A[rr][7];
        #pragma unroll
        for (int cc = 0; cc < 7; ++cc)
            if (cc > rr) s -= A[rr][cc] * Kv[cc];
        Kv[rr] = s / A[rr][rr];
    }
    #pragma unroll
    for (int l = 0; l < 7; ++l) K[b*7 + l] = (float)Kv[l];
}

// ---------------- x_new = x + K^T G (float4-vectorized) ----------------
__global__ void update_kernel(const float* __restrict__ x, const float* __restrict__ r,
                              const float* __restrict__ G1, const float* __restrict__ G2,
                              const float* __restrict__ K, float* __restrict__ out) {
    int b = blockIdx.z;
    int p4 = blockIdx.x*256 + threadIdx.x;
    float k0 = K[b*7+0], k1 = K[b*7+1], k2 = K[b*7+2], k3 = K[b*7+3];
    float k4 = K[b*7+4], k5 = K[b*7+5], k6 = K[b*7+6];
    size_t q  = (size_t)b*(NPIX/4) + p4;
    size_t q3 = (size_t)b*3*(NPIX/4) + p4;
    const float4* x4  = (const float4*)x;
    const float4* r4  = (const float4*)r;
    const float4* g14 = (const float4*)G1;
    const float4* g24 = (const float4*)G2;
    float4 xv = x4[q], rv = r4[q];
    float4 a = g14[q3], bb = g14[q3 + NPIX/4], c = g14[q3 + 2*(NPIX/4)];
    float4 d = g24[q3], e  = g24[q3 + NPIX/4], g = g24[q3 + 2*(NPIX/4)];
    float4 o;
    o.x = xv.x + k0*rv.x + k1*a.x + k2*bb.x + k3*c.x + k4*d.x + k5*e.x + k6*g.x;
    o.y = xv.y + k0*rv.y + k1*a.y + k2*bb.y + k3*c.y + k4*d.y + k5*e.y + k6*g.y;
    o.z = xv.z + k0*rv.z + k1*a.z + k2*bb.z + k3*c.z + k4*d.z + k5*e.z + k6*g.z;
    o.w = xv.w + k0*rv.w + k1*a.w + k2*bb.w + k3*c.w + k4*d.w + k5*e.w + k6*g.w;
    ((float4*)out)[q] = o;
}

extern "C" void kernel_launch(void* const* d_in, const int* in_sizes, int n_in,
                              void* d_out, int out_size, void* d_ws, size_t ws_size,
                              hipStream_t stream) {
    const float* x       = (const float*)d_in[0];
    const float* f       = (const float*)d_in[1];
    const float* kernelA = (const float*)d_in[2];
    const float* fc1_w1  = (const float*)d_in[3];
    const float* fc1_b1  = (const float*)d_in[4];
    const float* fc1_w2  = (const float*)d_in[5];
    const float* fc1_b2  = (const float*)d_in[6];
    const float* fc2_w1  = (const float*)d_in[7];
    const float* fc2_b1  = (const float*)d_in[8];
    const float* fc2_w2  = (const float*)d_in[9];
    const float* fc2_b2  = (const float*)d_in[10];
    float* out = (float*)d_out;

    const int B = in_sizes[2] / 9;

    double* Mws = (double*)d_ws;                    // B*28
    double* bws = Mws + (size_t)B*28;               // B*7
    float*  w1  = (float*)(bws + (size_t)B*7);      // B*147
    float*  w2  = w1 + (size_t)B*147;               // B*441
    float*  Kv  = w2 + (size_t)B*441;               // B*7
    float*  r   = Kv + (size_t)B*7 + 1;             // B*NPIX
    float*  G1  = r  + (size_t)B*NPIX;              // B*3*NPIX
    float*  G2  = G1 + (size_t)B*3*NPIX;            // B*3*NPIX
    float*  partial = G2 + (size_t)B*3*NPIX;        // B*NENT*RBLK

    dim3 cblk(64, 4);
    dim3 rgrd(MU/64, MU/16, B);    // residual + g2gram (64x16 tiles)
    dim3 g1grd(MU/128, MU/16, B);  // conv7_g1 (2 cols x 4 rows/thread)

    hipLaunchKernelGGL(mlp_kernel, dim3(B), dim3(256), 0, stream,
                       kernelA, fc1_w1, fc1_b1, fc1_w2, fc1_b2,
                       fc2_w1, fc2_b1, fc2_w2, fc2_b2, w1, w2);
    hipLaunchKernelGGL(residual_kernel, rgrd, cblk, 0, stream, x, f, kernelA, r);
    hipLaunchKernelGGL(conv7_g1, g1grd, cblk, 0, stream, r, w1, G1);
    hipLaunchKernelGGL(g2gram_kernel, rgrd, cblk, 0, stream, G1, r, w2, kernelA, G2, partial);
    hipLaunchKernelGGL(reduce2_kernel, dim3(B), dim3(256), 0, stream, partial, Mws, bws);
    hipLaunchKernelGGL(solve_kernel, dim3((B + 63)/64), dim3(64), 0, stream, Mws, bws, Kv, B);
    hipLaunchKernelGGL(update_kernel, dim3(NPIX/1024, 1, B), dim3(256), 0, stream,
                       x, r, G1, G2, Kv, out);
}

// Round 13
// 201.649 us; speedup vs baseline: 1.3509x; 1.3509x over previous
//
#include <hip/hip_runtime.h>

#define MU 256
#define NPIX (MU*MU)
#define ML 3
#define KS 7
#define LCH 7
#define NENT 35   // 28 upper-tri M entries + 7 b entries
#define RBLK 64   // partial blocks per sample in reduce stage-1

// ---------------- MLP: per-sample dynamic kernels ----------------
__global__ void mlp_kernel(const float* __restrict__ kernelA,
                           const float* __restrict__ fc1_w1, const float* __restrict__ fc1_b1,
                           const float* __restrict__ fc1_w2, const float* __restrict__ fc1_b2,
                           const float* __restrict__ fc2_w1, const float* __restrict__ fc2_b1,
                           const float* __restrict__ fc2_w2, const float* __restrict__ fc2_b2,
                           float* __restrict__ w1_out, float* __restrict__ w2_out) {
    int b = blockIdx.x;
    int t = threadIdx.x;
    __shared__ float kA[9];
    __shared__ float h1[200], h2[200];
    if (t < 9) kA[t] = kernelA[b*9 + t];
    __syncthreads();
    if (t < 200) {
        float s1 = fc1_b1[t], s2 = fc2_b1[t];
        #pragma unroll
        for (int i = 0; i < 9; ++i) {
            s1 += kA[i] * fc1_w1[i*200 + t];
            s2 += kA[i] * fc2_w1[i*200 + t];
        }
        h1[t] = fmaxf(s1, 0.f);
        h2[t] = fmaxf(s2, 0.f);
    }
    __syncthreads();
    if (t < 147) {
        float s = fc1_b2[t];
        for (int i = 0; i < 200; ++i) s += h1[i] * fc1_w2[i*147 + t];
        w1_out[b*147 + t] = s;
    }
    for (int o = t; o < 441; o += 256) {
        float s = fc2_b2[o];
        for (int i = 0; i < 200; ++i) s += h2[i] * fc2_w2[i*441 + o];
        w2_out[b*441 + o] = s;
    }
}

// ---- r = f - conv3x3(x, kernelA). Block (64,4), float4-staged LDS tile. ----
__global__ __launch_bounds__(256, 4) void residual_kernel(
        const float* __restrict__ x, const float* __restrict__ f,
        const float* __restrict__ kA, float* __restrict__ r) {
    int b = blockIdx.z;
    __shared__ float tile[18][72];
    int tx = threadIdx.x, ty = threadIdx.y;
    int tid = ty*64 + tx;
    float k[9];
    #pragma unroll
    for (int i = 0; i < 9; ++i) k[i] = kA[b*9 + i];
    int x0 = blockIdx.x*64, ysub = blockIdx.y*16;
    const float* xb = x + (size_t)b*NPIX;

    for (int u = tid; u < 18*18; u += 256) {
        int row = u / 18, q4 = u % 18;
        int yy = ysub + row - 1;
        int xx = x0 - 4 + q4*4;
        float4 vv = make_float4(0.f, 0.f, 0.f, 0.f);
        if (yy >= 0 && yy < MU && xx >= 0 && xx < MU)
            vv = *(const float4*)(xb + yy*MU + xx);
        *(float4*)&tile[row][q4*4] = vv;
    }
    __syncthreads();

    int ry = ty*4;
    float S0 = 0.f, S1 = 0.f, S2 = 0.f, S3 = 0.f;
    #pragma unroll
    for (int t = 0; t < 6; ++t) {
        float v0 = tile[ry + t][tx + 3];
        float v1 = tile[ry + t][tx + 4];
        float v2 = tile[ry + t][tx + 5];
        float e0 = v0*k[0] + v1*k[1] + v2*k[2];
        float e1 = v0*k[3] + v1*k[4] + v2*k[5];
        float e2 = v0*k[6] + v1*k[7] + v2*k[8];
        if (t == 0) { S0 += e0; }
        if (t == 1) { S1 += e0; S0 += e1; }
        if (t == 2) { S2 += e0; S1 += e1; S0 += e2; }
        if (t == 3) { S3 += e0; S2 += e1; S1 += e2; }
        if (t == 4) {           S3 += e1; S2 += e2; }
        if (t == 5) {                     S3 += e2; }
    }
    float Sv[4] = {S0, S1, S2, S3};
    #pragma unroll
    for (int dy = 0; dy < 4; ++dy) {
        size_t p = (size_t)b*NPIX + (size_t)(ysub + ry + dy)*MU + x0 + tx;
        r[p] = f[p] - Sv[dy];
    }
}

// ---- conv7x7 1->3ch. Block (64,4), 2 cols x 4 rows per thread (8 px),
//      tile[22][136] staged as float4, b64 LDS reads, SGPR weights. ----
__global__ __launch_bounds__(256) void conv7_g1(
        const float* __restrict__ r, const float* __restrict__ w1,
        float* __restrict__ G1) {
    int b = blockIdx.z;
    __shared__ float tile[22][136];
    int tx = threadIdx.x;
    int ty = threadIdx.y;
    int tid = ty*64 + tx;
    int x0 = blockIdx.x*128, y0 = blockIdx.y*16;
    const float* rb = r + (size_t)b*NPIX;
    const float* wgt = w1 + (size_t)b*147;

    for (int u = tid; u < 22*34; u += 256) {
        int row = u / 34, q4 = u % 34;
        int yy = y0 + row - 3;
        int xx = x0 - 4 + q4*4;
        float4 vv = make_float4(0.f, 0.f, 0.f, 0.f);
        if (yy >= 0 && yy < MU && xx >= 0 && xx < MU)
            vv = *(const float4*)(rb + yy*MU + xx);
        *(float4*)&tile[row][q4*4] = vv;
    }
    __syncthreads();

    float accA[3][4], accB[3][4];
    #pragma unroll
    for (int co = 0; co < 3; ++co)
        #pragma unroll
        for (int dy = 0; dy < 4; ++dy) { accA[co][dy] = 0.f; accB[co][dy] = 0.f; }

    int ry = ty*4;
    #pragma unroll
    for (int ir = 0; ir < 10; ++ir) {
        float v[10];
        #pragma unroll
        for (int h = 0; h < 5; ++h)
            *(float2*)&v[h*2] = *(float2*)&tile[ry + ir][2*tx + h*2];
        #pragma unroll
        for (int dy = 0; dy < 4; ++dy) {
            int i = ir - dy;
            if (i >= 0 && i <= 6) {
                #pragma unroll
                for (int co = 0; co < 3; ++co)
                    #pragma unroll
                    for (int j = 0; j < 7; ++j) {
                        float w = wgt[(co*7 + i)*7 + j];
                        accA[co][dy] += v[1 + j] * w;
                        accB[co][dy] += v[2 + j] * w;
                    }
            }
        }
    }
    #pragma unroll
    for (int dy = 0; dy < 4; ++dy) {
        size_t p = (size_t)b*3*NPIX + (size_t)(y0 + ry + dy)*MU + x0 + 2*tx;
        #pragma unroll
        for (int co = 0; co < 3; ++co)
            *(float2*)&G1[p + (size_t)co*NPIX] = make_float2(accA[co][dy], accB[co][dy]);
    }
}

// ---- conv7x7 3->3ch. Block (32,4)=128thr, tile[3][14][136] (22.8 KB),
//      4 cols x 2 rows per thread: 6 b64 reads serve 4 output cols
//      (18 LDS reads/px vs 30). SGPR weights, float4 output. ----
__global__ __launch_bounds__(128) void conv7_g2(
        const float* __restrict__ G1, const float* __restrict__ w2,
        float* __restrict__ G2) {
    int b = blockIdx.z;
    __shared__ float tile[3][14][136];
    int tx = threadIdx.x;              // 0..31 -> cols 4tx..4tx+3
    int ty = threadIdx.y;              // 0..3  -> output rows 2ty, 2ty+1
    int tid = ty*32 + tx;
    int x0 = blockIdx.x*128, y0 = blockIdx.y*8;
    const float* g1b = G1 + (size_t)b*3*NPIX;
    const float* wgt = w2 + (size_t)b*441;

    for (int u = tid; u < 3*14*34; u += 128) {
        int c = u / (14*34);
        int rem = u % (14*34);
        int row = rem / 34, q4 = rem % 34;
        int yy = y0 + row - 3;
        int xx = x0 - 4 + q4*4;
        float4 vv = make_float4(0.f, 0.f, 0.f, 0.f);
        if (yy >= 0 && yy < MU && xx >= 0 && xx < MU)
            vv = *(const float4*)(g1b + (size_t)c*NPIX + yy*MU + xx);
        *(float4*)&tile[c][row][q4*4] = vv;
    }
    __syncthreads();

    float acc[3][2][4];
    #pragma unroll
    for (int co = 0; co < 3; ++co)
        #pragma unroll
        for (int dy = 0; dy < 2; ++dy)
            #pragma unroll
            for (int cc = 0; cc < 4; ++cc) acc[co][dy][cc] = 0.f;

    int ry = ty*2;
    #pragma unroll
    for (int c = 0; c < 3; ++c) {
        #pragma unroll
        for (int ir = 0; ir < 8; ++ir) {
            // v[0..11] = tile cols 4tx .. 4tx+11; output col cc uses v[cc+j+1]
            float v[12];
            #pragma unroll
            for (int h = 0; h < 6; ++h)
                *(float2*)&v[h*2] = *(float2*)&tile[c][ry + ir][4*tx + h*2];
            #pragma unroll
            for (int dy = 0; dy < 2; ++dy) {
                int i = ir - dy;
                if (i >= 0 && i <= 6) {
                    #pragma unroll
                    for (int co = 0; co < 3; ++co)
                        #pragma unroll
                        for (int j = 0; j < 7; ++j) {
                            float w = wgt[((co*3 + c)*7 + i)*7 + j];
                            #pragma unroll
                            for (int cc = 0; cc < 4; ++cc)
                                acc[co][dy][cc] += v[cc + j + 1] * w;
                        }
                }
            }
        }
    }
    #pragma unroll
    for (int dy = 0; dy < 2; ++dy) {
        size_t p = (size_t)b*3*NPIX + (size_t)(y0 + ry + dy)*MU + x0 + 4*tx;
        #pragma unroll
        for (int co = 0; co < 3; ++co)
            *(float4*)&G2[p + (size_t)co*NPIX] =
                make_float4(acc[co][dy][0], acc[co][dy][1], acc[co][dy][2], acc[co][dy][3]);
    }
}

// ---- S = depthwise3x3(G, kernelA); stage-1 Gram partials.
//      Butterfly SPLIT-reduction: 63 shfl total (vs 35x6=210). ----
__global__ __launch_bounds__(256, 4) void reduce_kernel(
        const float* __restrict__ r, const float* __restrict__ G1,
        const float* __restrict__ G2, const float* __restrict__ kA,
        float* __restrict__ partial) {
    int b = blockIdx.z;
    __shared__ float tile[7][18][72];
    __shared__ float wsum[NENT][4];
    int tx = threadIdx.x;          // 0..63 = lane; wave == one ty
    int ty = threadIdx.y;          // 0..3
    int tid = ty*64 + tx;
    float k[9];
    #pragma unroll
    for (int i = 0; i < 9; ++i) k[i] = kA[b*9 + i];

    const float* srcs[7] = {
        r  + (size_t)b*NPIX,
        G1 + (size_t)b*3*NPIX, G1 + (size_t)b*3*NPIX + NPIX, G1 + (size_t)b*3*NPIX + 2*NPIX,
        G2 + (size_t)b*3*NPIX, G2 + (size_t)b*3*NPIX + NPIX, G2 + (size_t)b*3*NPIX + 2*NPIX
    };

    int x0 = blockIdx.x*64;
    int ysub = blockIdx.y*16;

    #pragma unroll
    for (int c = 0; c < 7; ++c) {
        const float* src = srcs[c];
        for (int u = tid; u < 18*18; u += 256) {
            int row = u / 18, q4 = u % 18;
            int yy = ysub + row - 1;
            int xx = x0 - 4 + q4*4;
            float4 vv = make_float4(0.f, 0.f, 0.f, 0.f);
            if (yy >= 0 && yy < MU && xx >= 0 && xx < MU)
                vv = *(const float4*)(src + yy*MU + xx);
            *(float4*)&tile[c][row][q4*4] = vv;
        }
    }
    __syncthreads();

    float acc[64];
    #pragma unroll
    for (int e = 0; e < 64; ++e) acc[e] = 0.f;

    int ry = ty*4;
    float S_all[7][4];
    #pragma unroll
    for (int c = 0; c < 7; ++c) {
        float S0 = 0.f, S1 = 0.f, S2 = 0.f, S3 = 0.f;
        #pragma unroll
        for (int t = 0; t < 6; ++t) {
            float v0 = tile[c][ry + t][tx + 3];
            float v1 = tile[c][ry + t][tx + 4];
            float v2 = tile[c][ry + t][tx + 5];
            float e0 = v0*k[0] + v1*k[1] + v2*k[2];
            float e1 = v0*k[3] + v1*k[4] + v2*k[5];
            float e2 = v0*k[6] + v1*k[7] + v2*k[8];
            if (t == 0) { S0 += e0; }
            if (t == 1) { S1 += e0; S0 += e1; }
            if (t == 2) { S2 += e0; S1 += e1; S0 += e2; }
            if (t == 3) { S3 += e0; S2 += e1; S1 += e2; }
            if (t == 4) {           S3 += e1; S2 += e2; }
            if (t == 5) {                     S3 += e2; }
        }
        S_all[c][0] = S0; S_all[c][1] = S1; S_all[c][2] = S2; S_all[c][3] = S3;
    }
    #pragma unroll
    for (int dy = 0; dy < 4; ++dy) {
        float rv = tile[0][ry + dy + 1][tx + 4];
        int idx = 0;
        #pragma unroll
        for (int l = 0; l < 7; ++l) {
            #pragma unroll
            for (int m = l; m < 7; ++m) {
                acc[idx] += S_all[l][dy] * S_all[m][dy];
                ++idx;
            }
        }
        #pragma unroll
        for (int l = 0; l < 7; ++l) acc[28 + l] += S_all[l][dy] * rv;
    }

    // butterfly split-reduce: lane ends holding full sum of entry bitrev6(lane)
    #pragma unroll
    for (int step = 0; step < 6; ++step) {
        const int mask = 1 << step;
        const int nh = 32 >> step;
        bool hi = (tx & mask) != 0;
        #pragma unroll
        for (int i = 0; i < nh; ++i) {
            float send = hi ? acc[i] : acc[i + nh];
            float got = __shfl_xor(send, mask);
            acc[i] = (hi ? acc[i + nh] : acc[i]) + got;
        }
    }
    int ent = ((tx&1)<<5) | ((tx&2)<<3) | ((tx&4)<<1)
            | ((tx&8)>>1) | ((tx&16)>>3) | ((tx&32)>>5);
    if (ent < NENT) wsum[ent][ty] = acc[0];
    __syncthreads();
    if (tid < NENT) {
        float s = wsum[tid][0] + wsum[tid][1] + wsum[tid][2] + wsum[tid][3];
        int blockLinear = blockIdx.y*4 + blockIdx.x;   // 0..63
        partial[((size_t)b*NENT + tid)*RBLK + blockLinear] = s;
    }
}

// ---- stage-2: sum RBLK per-block partials per (sample, entry) in f64 ----
__global__ void reduce2_kernel(const float* __restrict__ partial,
                               double* __restrict__ M, double* __restrict__ bv) {
    int b = blockIdx.x;
    int wave = threadIdx.x >> 6;
    int lane = threadIdx.x & 63;
    for (int e = wave; e < NENT; e += 4) {
        const float* p = partial + ((size_t)b*NENT + e)*RBLK;
        double s = (double)p[lane];
        #pragma unroll
        for (int off = 32; off; off >>= 1) s += __shfl_down(s, off);
        if (lane == 0) {
            if (e < 28) M[b*28 + e] = s;
            else        bv[b*7 + (e - 28)] = s;
        }
    }
}

// ---- per-sample 7x7 solve: f64, partial pivoting, ALL-STATIC indexing ----
__global__ __launch_bounds__(64, 1) void solve_kernel(
        const double* __restrict__ M, const double* __restrict__ bv,
        float* __restrict__ K, int B) {
    int b = blockIdx.x*64 + threadIdx.x;
    if (b >= B) return;
    double A[7][8];
    int idx = 0;
    #pragma unroll
    for (int l = 0; l < 7; ++l)
        #pragma unroll
        for (int m = l; m < 7; ++m) {
            double v = M[b*28 + idx];
            A[l][m] = v;
            A[m][l] = v;
            ++idx;
        }
    #pragma unroll
    for (int l = 0; l < 7; ++l) A[l][7] = bv[b*7 + l];

    #pragma unroll
    for (int col = 0; col < 7; ++col) {
        int piv = col;
        double mx = fabs(A[col][col]);
        #pragma unroll
        for (int rr = 0; rr < 7; ++rr) {
            if (rr > col) {
                double a = fabs(A[rr][col]);
                if (a > mx) { mx = a; piv = rr; }
            }
        }
        #pragma unroll
        for (int rr = 0; rr < 7; ++rr) {
            if (rr > col) {
                bool c = (rr == piv);
                #pragma unroll
                for (int cc = 0; cc < 8; ++cc) {
                    double t0 = A[col][cc], t1 = A[rr][cc];
                    A[col][cc] = c ? t1 : t0;
                    A[rr][cc]  = c ? t0 : t1;
                }
            }
        }
        double d = A[col][col];
        #pragma unroll
        for (int rr = 0; rr < 7; ++rr) {
            if (rr > col) {
                double fct = A[rr][col] / d;
                #pragma unroll
                for (int cc = 0; cc < 8; ++cc) A[rr][cc] -= fct * A[col][cc];
            }
        }
    }
    double Kv[7];
    #pragma unroll
    for (int rr = 6; rr >= 0; --rr) {
        double s = A[rr][7];
        #pragma unroll
        for (int cc = 0; cc < 7; ++cc)
            if (cc > rr) s -= A[rr][cc] * Kv[cc];
        Kv[rr] = s / A[rr][rr];
    }
    #pragma unroll
    for (int l = 0; l < 7; ++l) K[b*7 + l] = (float)Kv[l];
}

// ---------------- x_new = x + K^T G (float4-vectorized) ----------------
__global__ void update_kernel(const float* __restrict__ x, const float* __restrict__ r,
                              const float* __restrict__ G1, const float* __restrict__ G2,
                              const float* __restrict__ K, float* __restrict__ out) {
    int b = blockIdx.z;
    int p4 = blockIdx.x*256 + threadIdx.x;
    float k0 = K[b*7+0], k1 = K[b*7+1], k2 = K[b*7+2], k3 = K[b*7+3];
    float k4 = K[b*7+4], k5 = K[b*7+5], k6 = K[b*7+6];
    size_t q  = (size_t)b*(NPIX/4) + p4;
    size_t q3 = (size_t)b*3*(NPIX/4) + p4;
    const float4* x4  = (const float4*)x;
    const float4* r4  = (const float4*)r;
    const float4* g14 = (const float4*)G1;
    const float4* g24 = (const float4*)G2;
    float4 xv = x4[q], rv = r4[q];
    float4 a = g14[q3], bb = g14[q3 + NPIX/4], c = g14[q3 + 2*(NPIX/4)];
    float4 d = g24[q3], e  = g24[q3 + NPIX/4], g = g24[q3 + 2*(NPIX/4)];
    float4 o;
    o.x = xv.x + k0*rv.x + k1*a.x + k2*bb.x + k3*c.x + k4*d.x + k5*e.x + k6*g.x;
    o.y = xv.y + k0*rv.y + k1*a.y + k2*bb.y + k3*c.y + k4*d.y + k5*e.y + k6*g.y;
    o.z = xv.z + k0*rv.z + k1*a.z + k2*bb.z + k3*c.z + k4*d.z + k5*e.z + k6*g.z;
    o.w = xv.w + k0*rv.w + k1*a.w + k2*bb.w + k3*c.w + k4*d.w + k5*e.w + k6*g.w;
    ((float4*)out)[q] = o;
}

extern "C" void kernel_launch(void* const* d_in, const int* in_sizes, int n_in,
                              void* d_out, int out_size, void* d_ws, size_t ws_size,
                              hipStream_t stream) {
    const float* x       = (const float*)d_in[0];
    const float* f       = (const float*)d_in[1];
    const float* kernelA = (const float*)d_in[2];
    const float* fc1_w1  = (const float*)d_in[3];
    const float* fc1_b1  = (const float*)d_in[4];
    const float* fc1_w2  = (const float*)d_in[5];
    const float* fc1_b2  = (const float*)d_in[6];
    const float* fc2_w1  = (const float*)d_in[7];
    const float* fc2_b1  = (const float*)d_in[8];
    const float* fc2_w2  = (const float*)d_in[9];
    const float* fc2_b2  = (const float*)d_in[10];
    float* out = (float*)d_out;

    const int B = in_sizes[2] / 9;

    // workspace layout (doubles first for 8B alignment).
    // NOTE: no +1 after Kv — keeps r (and G1/G2/partial) 16B-aligned for
    // float4 loads (the old +1 misaligned ~70 MB of float4 traffic).
    double* Mws = (double*)d_ws;                    // B*28
    double* bws = Mws + (size_t)B*28;               // B*7
    float*  w1  = (float*)(bws + (size_t)B*7);      // B*147
    float*  w2  = w1 + (size_t)B*147;               // B*441
    float*  Kv  = w2 + (size_t)B*441;               // B*7
    float*  r   = Kv + (size_t)B*7;                 // B*NPIX (16B-aligned)
    float*  G1  = r  + (size_t)B*NPIX;              // B*3*NPIX
    float*  G2  = G1 + (size_t)B*3*NPIX;            // B*3*NPIX
    float*  partial = G2 + (size_t)B*3*NPIX;        // B*NENT*RBLK

    dim3 cblk(64, 4);
    dim3 rgrd(MU/64, MU/16, B);    // residual + reduce
    dim3 g1grd(MU/128, MU/16, B);  // conv7_g1 (2 cols x 4 rows/thread)
    dim3 g2blk(32, 4);
    dim3 g2grd(MU/128, MU/8, B);   // conv7_g2 (4 cols x 2 rows/thread)

    hipLaunchKernelGGL(mlp_kernel, dim3(B), dim3(256), 0, stream,
                       kernelA, fc1_w1, fc1_b1, fc1_w2, fc1_b2,
                       fc2_w1, fc2_b1, fc2_w2, fc2_b2, w1, w2);
    hipLaunchKernelGGL(residual_kernel, rgrd, cblk, 0, stream, x, f, kernelA, r);
    hipLaunchKernelGGL(conv7_g1, g1grd, cblk, 0, stream, r, w1, G1);
    hipLaunchKernelGGL(conv7_g2, g2grd, g2blk, 0, stream, G1, w2, G2);
    hipLaunchKernelGGL(reduce_kernel, rgrd, cblk, 0, stream, r, G1, G2, kernelA, partial);
    hipLaunchKernelGGL(reduce2_kernel, dim3(B), dim3(256), 0, stream, partial, Mws, bws);
    hipLaunchKernelGGL(solve_kernel, dim3((B + 63)/64), dim3(64), 0, stream, Mws, bws, Kv, B);
    hipLaunchKernelGGL(update_kernel, dim3(NPIX/1024, 1, B), dim3(256), 0, stream,
                       x, r, G1, G2, Kv, out);
}

// Round 14
// 195.011 us; speedup vs baseline: 1.3969x; 1.0340x over previous
//
#include <hip/hip_runtime.h>

#define MU 256
#define NPIX (MU*MU)
#define ML 3
#define KS 7
#define LCH 7
#define NENT 35   // 28 upper-tri M entries + 7 b entries
#define RBLK 64   // partial blocks per sample in reduce stage-1

// ---------------- MLP: per-sample dynamic kernels ----------------
__global__ void mlp_kernel(const float* __restrict__ kernelA,
                           const float* __restrict__ fc1_w1, const float* __restrict__ fc1_b1,
                           const float* __restrict__ fc1_w2, const float* __restrict__ fc1_b2,
                           const float* __restrict__ fc2_w1, const float* __restrict__ fc2_b1,
                           const float* __restrict__ fc2_w2, const float* __restrict__ fc2_b2,
                           float* __restrict__ w1_out, float* __restrict__ w2_out) {
    int b = blockIdx.x;
    int t = threadIdx.x;
    __shared__ float kA[9];
    __shared__ float h1[200], h2[200];
    if (t < 9) kA[t] = kernelA[b*9 + t];
    __syncthreads();
    if (t < 200) {
        float s1 = fc1_b1[t], s2 = fc2_b1[t];
        #pragma unroll
        for (int i = 0; i < 9; ++i) {
            s1 += kA[i] * fc1_w1[i*200 + t];
            s2 += kA[i] * fc2_w1[i*200 + t];
        }
        h1[t] = fmaxf(s1, 0.f);
        h2[t] = fmaxf(s2, 0.f);
    }
    __syncthreads();
    if (t < 147) {
        float s = fc1_b2[t];
        for (int i = 0; i < 200; ++i) s += h1[i] * fc1_w2[i*147 + t];
        w1_out[b*147 + t] = s;
    }
    for (int o = t; o < 441; o += 256) {
        float s = fc2_b2[o];
        for (int i = 0; i < 200; ++i) s += h2[i] * fc2_w2[i*441 + o];
        w2_out[b*441 + o] = s;
    }
}

// ---- r = f - conv3x3(x, kernelA). Block (64,4), float4-staged LDS tile. ----
__global__ __launch_bounds__(256, 4) void residual_kernel(
        const float* __restrict__ x, const float* __restrict__ f,
        const float* __restrict__ kA, float* __restrict__ r) {
    int b = blockIdx.z;
    __shared__ float tile[18][72];
    int tx = threadIdx.x, ty = threadIdx.y;
    int tid = ty*64 + tx;
    float k[9];
    #pragma unroll
    for (int i = 0; i < 9; ++i) k[i] = kA[b*9 + i];
    int x0 = blockIdx.x*64, ysub = blockIdx.y*16;
    const float* xb = x + (size_t)b*NPIX;

    for (int u = tid; u < 18*18; u += 256) {
        int row = u / 18, q4 = u % 18;
        int yy = ysub + row - 1;
        int xx = x0 - 4 + q4*4;
        float4 vv = make_float4(0.f, 0.f, 0.f, 0.f);
        if (yy >= 0 && yy < MU && xx >= 0 && xx < MU)
            vv = *(const float4*)(xb + yy*MU + xx);
        *(float4*)&tile[row][q4*4] = vv;
    }
    __syncthreads();

    int ry = ty*4;
    float S0 = 0.f, S1 = 0.f, S2 = 0.f, S3 = 0.f;
    #pragma unroll
    for (int t = 0; t < 6; ++t) {
        float v0 = tile[ry + t][tx + 3];
        float v1 = tile[ry + t][tx + 4];
        float v2 = tile[ry + t][tx + 5];
        float e0 = v0*k[0] + v1*k[1] + v2*k[2];
        float e1 = v0*k[3] + v1*k[4] + v2*k[5];
        float e2 = v0*k[6] + v1*k[7] + v2*k[8];
        if (t == 0) { S0 += e0; }
        if (t == 1) { S1 += e0; S0 += e1; }
        if (t == 2) { S2 += e0; S1 += e1; S0 += e2; }
        if (t == 3) { S3 += e0; S2 += e1; S1 += e2; }
        if (t == 4) {           S3 += e1; S2 += e2; }
        if (t == 5) {                     S3 += e2; }
    }
    float Sv[4] = {S0, S1, S2, S3};
    #pragma unroll
    for (int dy = 0; dy < 4; ++dy) {
        size_t p = (size_t)b*NPIX + (size_t)(ysub + ry + dy)*MU + x0 + tx;
        r[p] = f[p] - Sv[dy];
    }
}

// ---- conv7x7 1->3ch. Block (64,4), 2 cols x 4 rows per thread (8 px),
//      tile[22][136] staged as float4, b64 LDS reads, SGPR weights. ----
__global__ __launch_bounds__(256) void conv7_g1(
        const float* __restrict__ r, const float* __restrict__ w1,
        float* __restrict__ G1) {
    int b = blockIdx.z;
    __shared__ float tile[22][136];
    int tx = threadIdx.x;
    int ty = threadIdx.y;
    int tid = ty*64 + tx;
    int x0 = blockIdx.x*128, y0 = blockIdx.y*16;
    const float* rb = r + (size_t)b*NPIX;
    const float* wgt = w1 + (size_t)b*147;

    for (int u = tid; u < 22*34; u += 256) {
        int row = u / 34, q4 = u % 34;
        int yy = y0 + row - 3;
        int xx = x0 - 4 + q4*4;
        float4 vv = make_float4(0.f, 0.f, 0.f, 0.f);
        if (yy >= 0 && yy < MU && xx >= 0 && xx < MU)
            vv = *(const float4*)(rb + yy*MU + xx);
        *(float4*)&tile[row][q4*4] = vv;
    }
    __syncthreads();

    float accA[3][4], accB[3][4];
    #pragma unroll
    for (int co = 0; co < 3; ++co)
        #pragma unroll
        for (int dy = 0; dy < 4; ++dy) { accA[co][dy] = 0.f; accB[co][dy] = 0.f; }

    int ry = ty*4;
    #pragma unroll
    for (int ir = 0; ir < 10; ++ir) {
        float v[10];
        #pragma unroll
        for (int h = 0; h < 5; ++h)
            *(float2*)&v[h*2] = *(float2*)&tile[ry + ir][2*tx + h*2];
        #pragma unroll
        for (int dy = 0; dy < 4; ++dy) {
            int i = ir - dy;
            if (i >= 0 && i <= 6) {
                #pragma unroll
                for (int co = 0; co < 3; ++co)
                    #pragma unroll
                    for (int j = 0; j < 7; ++j) {
                        float w = wgt[(co*7 + i)*7 + j];
                        accA[co][dy] += v[1 + j] * w;
                        accB[co][dy] += v[2 + j] * w;
                    }
            }
        }
    }
    #pragma unroll
    for (int dy = 0; dy < 4; ++dy) {
        size_t p = (size_t)b*3*NPIX + (size_t)(y0 + ry + dy)*MU + x0 + 2*tx;
        #pragma unroll
        for (int co = 0; co < 3; ++co)
            *(float2*)&G1[p + (size_t)co*NPIX] = make_float2(accA[co][dy], accB[co][dy]);
    }
}

// ---- conv7x7 3->3ch. R9 configuration (best measured: 63 us):
//      tile[3][14][136] = 22.8 KB, block (64,4), 2 cols x 2 rows/thread. ----
__global__ __launch_bounds__(256) void conv7_g2(
        const float* __restrict__ G1, const float* __restrict__ w2,
        float* __restrict__ G2) {
    int b = blockIdx.z;
    __shared__ float tile[3][14][136];
    int tx = threadIdx.x;
    int ty = threadIdx.y;
    int tid = ty*64 + tx;
    int x0 = blockIdx.x*128, y0 = blockIdx.y*8;
    const float* g1b = G1 + (size_t)b*3*NPIX;
    const float* wgt = w2 + (size_t)b*441;

    for (int u = tid; u < 3*14*34; u += 256) {
        int c = u / (14*34);
        int rem = u % (14*34);
        int row = rem / 34, q4 = rem % 34;
        int yy = y0 + row - 3;
        int xx = x0 - 4 + q4*4;
        float4 vv = make_float4(0.f, 0.f, 0.f, 0.f);
        if (yy >= 0 && yy < MU && xx >= 0 && xx < MU)
            vv = *(const float4*)(g1b + (size_t)c*NPIX + yy*MU + xx);
        *(float4*)&tile[c][row][q4*4] = vv;
    }
    __syncthreads();

    float accA[3][2], accB[3][2];
    #pragma unroll
    for (int co = 0; co < 3; ++co)
        #pragma unroll
        for (int dy = 0; dy < 2; ++dy) { accA[co][dy] = 0.f; accB[co][dy] = 0.f; }

    int ry = ty*2;
    #pragma unroll
    for (int c = 0; c < 3; ++c) {
        #pragma unroll
        for (int ir = 0; ir < 8; ++ir) {
            float v[10];
            #pragma unroll
            for (int h = 0; h < 5; ++h)
                *(float2*)&v[h*2] = *(float2*)&tile[c][ry + ir][2*tx + h*2];
            #pragma unroll
            for (int dy = 0; dy < 2; ++dy) {
                int i = ir - dy;
                if (i >= 0 && i <= 6) {
                    #pragma unroll
                    for (int co = 0; co < 3; ++co)
                        #pragma unroll
                        for (int j = 0; j < 7; ++j) {
                            float w = wgt[((co*3 + c)*7 + i)*7 + j];
                            accA[co][dy] += v[1 + j] * w;
                            accB[co][dy] += v[2 + j] * w;
                        }
                }
            }
        }
    }
    #pragma unroll
    for (int dy = 0; dy < 2; ++dy) {
        size_t p = (size_t)b*3*NPIX + (size_t)(y0 + ry + dy)*MU + x0 + 2*tx;
        #pragma unroll
        for (int co = 0; co < 3; ++co)
            *(float2*)&G2[p + (size_t)co*NPIX] = make_float2(accA[co][dy], accB[co][dy]);
    }
}

// ---- S = depthwise3x3(G, kernelA); stage-1 Gram partials.
//      Butterfly SPLIT-reduction: 63 shfl total (vs 35x6=210). ----
__global__ __launch_bounds__(256, 4) void reduce_kernel(
        const float* __restrict__ r, const float* __restrict__ G1,
        const float* __restrict__ G2, const float* __restrict__ kA,
        float* __restrict__ partial) {
    int b = blockIdx.z;
    __shared__ float tile[7][18][72];
    __shared__ float wsum[NENT][4];
    int tx = threadIdx.x;          // 0..63 = lane; wave == one ty
    int ty = threadIdx.y;          // 0..3
    int tid = ty*64 + tx;
    float k[9];
    #pragma unroll
    for (int i = 0; i < 9; ++i) k[i] = kA[b*9 + i];

    const float* srcs[7] = {
        r  + (size_t)b*NPIX,
        G1 + (size_t)b*3*NPIX, G1 + (size_t)b*3*NPIX + NPIX, G1 + (size_t)b*3*NPIX + 2*NPIX,
        G2 + (size_t)b*3*NPIX, G2 + (size_t)b*3*NPIX + NPIX, G2 + (size_t)b*3*NPIX + 2*NPIX
    };

    int x0 = blockIdx.x*64;
    int ysub = blockIdx.y*16;

    #pragma unroll
    for (int c = 0; c < 7; ++c) {
        const float* src = srcs[c];
        for (int u = tid; u < 18*18; u += 256) {
            int row = u / 18, q4 = u % 18;
            int yy = ysub + row - 1;
            int xx = x0 - 4 + q4*4;
            float4 vv = make_float4(0.f, 0.f, 0.f, 0.f);
            if (yy >= 0 && yy < MU && xx >= 0 && xx < MU)
                vv = *(const float4*)(src + yy*MU + xx);
            *(float4*)&tile[c][row][q4*4] = vv;
        }
    }
    __syncthreads();

    float acc[64];
    #pragma unroll
    for (int e = 0; e < 64; ++e) acc[e] = 0.f;

    int ry = ty*4;
    float S_all[7][4];
    #pragma unroll
    for (int c = 0; c < 7; ++c) {
        float S0 = 0.f, S1 = 0.f, S2 = 0.f, S3 = 0.f;
        #pragma unroll
        for (int t = 0; t < 6; ++t) {
            float v0 = tile[c][ry + t][tx + 3];
            float v1 = tile[c][ry + t][tx + 4];
            float v2 = tile[c][ry + t][tx + 5];
            float e0 = v0*k[0] + v1*k[1] + v2*k[2];
            float e1 = v0*k[3] + v1*k[4] + v2*k[5];
            float e2 = v0*k[6] + v1*k[7] + v2*k[8];
            if (t == 0) { S0 += e0; }
            if (t == 1) { S1 += e0; S0 += e1; }
            if (t == 2) { S2 += e0; S1 += e1; S0 += e2; }
            if (t == 3) { S3 += e0; S2 += e1; S1 += e2; }
            if (t == 4) {           S3 += e1; S2 += e2; }
            if (t == 5) {                     S3 += e2; }
        }
        S_all[c][0] = S0; S_all[c][1] = S1; S_all[c][2] = S2; S_all[c][3] = S3;
    }
    #pragma unroll
    for (int dy = 0; dy < 4; ++dy) {
        float rv = tile[0][ry + dy + 1][tx + 4];
        int idx = 0;
        #pragma unroll
        for (int l = 0; l < 7; ++l) {
            #pragma unroll
            for (int m = l; m < 7; ++m) {
                acc[idx] += S_all[l][dy] * S_all[m][dy];
                ++idx;
            }
        }
        #pragma unroll
        for (int l = 0; l < 7; ++l) acc[28 + l] += S_all[l][dy] * rv;
    }

    // butterfly split-reduce: lane ends holding full sum of entry bitrev6(lane)
    #pragma unroll
    for (int step = 0; step < 6; ++step) {
        const int mask = 1 << step;
        const int nh = 32 >> step;
        bool hi = (tx & mask) != 0;
        #pragma unroll
        for (int i = 0; i < nh; ++i) {
            float send = hi ? acc[i] : acc[i + nh];
            float got = __shfl_xor(send, mask);
            acc[i] = (hi ? acc[i + nh] : acc[i]) + got;
        }
    }
    int ent = ((tx&1)<<5) | ((tx&2)<<3) | ((tx&4)<<1)
            | ((tx&8)>>1) | ((tx&16)>>3) | ((tx&32)>>5);
    if (ent < NENT) wsum[ent][ty] = acc[0];
    __syncthreads();
    if (tid < NENT) {
        float s = wsum[tid][0] + wsum[tid][1] + wsum[tid][2] + wsum[tid][3];
        int blockLinear = blockIdx.y*4 + blockIdx.x;   // 0..63
        partial[((size_t)b*NENT + tid)*RBLK + blockLinear] = s;
    }
}

// ---- stage-2: sum RBLK per-block partials per (sample, entry) in f64 ----
__global__ void reduce2_kernel(const float* __restrict__ partial,
                               double* __restrict__ M, double* __restrict__ bv) {
    int b = blockIdx.x;
    int wave = threadIdx.x >> 6;
    int lane = threadIdx.x & 63;
    for (int e = wave; e < NENT; e += 4) {
        const float* p = partial + ((size_t)b*NENT + e)*RBLK;
        double s = (double)p[lane];
        #pragma unroll
        for (int off = 32; off; off >>= 1) s += __shfl_down(s, off);
        if (lane == 0) {
            if (e < 28) M[b*28 + e] = s;
            else        bv[b*7 + (e - 28)] = s;
        }
    }
}

// ---- per-sample 7x7 solve: f64, partial pivoting, ALL-STATIC indexing ----
__global__ __launch_bounds__(64, 1) void solve_kernel(
        const double* __restrict__ M, const double* __restrict__ bv,
        float* __restrict__ K, int B) {
    int b = blockIdx.x*64 + threadIdx.x;
    if (b >= B) return;
    double A[7][8];
    int idx = 0;
    #pragma unroll
    for (int l = 0; l < 7; ++l)
        #pragma unroll
        for (int m = l; m < 7; ++m) {
            double v = M[b*28 + idx];
            A[l][m] = v;
            A[m][l] = v;
            ++idx;
        }
    #pragma unroll
    for (int l = 0; l < 7; ++l) A[l][7] = bv[b*7 + l];

    #pragma unroll
    for (int col = 0; col < 7; ++col) {
        int piv = col;
        double mx = fabs(A[col][col]);
        #pragma unroll
        for (int rr = 0; rr < 7; ++rr) {
            if (rr > col) {
                double a = fabs(A[rr][col]);
                if (a > mx) { mx = a; piv = rr; }
            }
        }
        #pragma unroll
        for (int rr = 0; rr < 7; ++rr) {
            if (rr > col) {
                bool c = (rr == piv);
                #pragma unroll
                for (int cc = 0; cc < 8; ++cc) {
                    double t0 = A[col][cc], t1 = A[rr][cc];
                    A[col][cc] = c ? t1 : t0;
                    A[rr][cc]  = c ? t0 : t1;
                }
            }
        }
        double d = A[col][col];
        #pragma unroll
        for (int rr = 0; rr < 7; ++rr) {
            if (rr > col) {
                double fct = A[rr][col] / d;
                #pragma unroll
                for (int cc = 0; cc < 8; ++cc) A[rr][cc] -= fct * A[col][cc];
            }
        }
    }
    double Kv[7];
    #pragma unroll
    for (int rr = 6; rr >= 0; --rr) {
        double s = A[rr][7];
        #pragma unroll
        for (int cc = 0; cc < 7; ++cc)
            if (cc > rr) s -= A[rr][cc] * Kv[cc];
        Kv[rr] = s / A[rr][rr];
    }
    #pragma unroll
    for (int l = 0; l < 7; ++l) K[b*7 + l] = (float)Kv[l];
}

// ---------------- x_new = x + K^T G (float4-vectorized) ----------------
__global__ void update_kernel(const float* __restrict__ x, const float* __restrict__ r,
                              const float* __restrict__ G1, const float* __restrict__ G2,
                              const float* __restrict__ K, float* __restrict__ out) {
    int b = blockIdx.z;
    int p4 = blockIdx.x*256 + threadIdx.x;
    float k0 = K[b*7+0], k1 = K[b*7+1], k2 = K[b*7+2], k3 = K[b*7+3];
    float k4 = K[b*7+4], k5 = K[b*7+5], k6 = K[b*7+6];
    size_t q  = (size_t)b*(NPIX/4) + p4;
    size_t q3 = (size_t)b*3*(NPIX/4) + p4;
    const float4* x4  = (const float4*)x;
    const float4* r4  = (const float4*)r;
    const float4* g14 = (const float4*)G1;
    const float4* g24 = (const float4*)G2;
    float4 xv = x4[q], rv = r4[q];
    float4 a = g14[q3], bb = g14[q3 + NPIX/4], c = g14[q3 + 2*(NPIX/4)];
    float4 d = g24[q3], e  = g24[q3 + NPIX/4], g = g24[q3 + 2*(NPIX/4)];
    float4 o;
    o.x = xv.x + k0*rv.x + k1*a.x + k2*bb.x + k3*c.x + k4*d.x + k5*e.x + k6*g.x;
    o.y = xv.y + k0*rv.y + k1*a.y + k2*bb.y + k3*c.y + k4*d.y + k5*e.y + k6*g.y;
    o.z = xv.z + k0*rv.z + k1*a.z + k2*bb.z + k3*c.z + k4*d.z + k5*e.z + k6*g.z;
    o.w = xv.w + k0*rv.w + k1*a.w + k2*bb.w + k3*c.w + k4*d.w + k5*e.w + k6*g.w;
    ((float4*)out)[q] = o;
}

extern "C" void kernel_launch(void* const* d_in, const int* in_sizes, int n_in,
                              void* d_out, int out_size, void* d_ws, size_t ws_size,
                              hipStream_t stream) {
    const float* x       = (const float*)d_in[0];
    const float* f       = (const float*)d_in[1];
    const float* kernelA = (const float*)d_in[2];
    const float* fc1_w1  = (const float*)d_in[3];
    const float* fc1_b1  = (const float*)d_in[4];
    const float* fc1_w2  = (const float*)d_in[5];
    const float* fc1_b2  = (const float*)d_in[6];
    const float* fc2_w1  = (const float*)d_in[7];
    const float* fc2_b1  = (const float*)d_in[8];
    const float* fc2_w2  = (const float*)d_in[9];
    const float* fc2_b2  = (const float*)d_in[10];
    float* out = (float*)d_out;

    const int B = in_sizes[2] / 9;

    // workspace layout (doubles first for 8B alignment).
    // NOTE: no +1 after Kv — keeps r (and G1/G2/partial) 16B-aligned for
    // float4 loads (the old +1 misaligned ~70 MB of float4 traffic).
    double* Mws = (double*)d_ws;                    // B*28
    double* bws = Mws + (size_t)B*28;               // B*7
    float*  w1  = (float*)(bws + (size_t)B*7);      // B*147
    float*  w2  = w1 + (size_t)B*147;               // B*441
    float*  Kv  = w2 + (size_t)B*441;               // B*7
    float*  r   = Kv + (size_t)B*7;                 // B*NPIX (16B-aligned)
    float*  G1  = r  + (size_t)B*NPIX;              // B*3*NPIX
    float*  G2  = G1 + (size_t)B*3*NPIX;            // B*3*NPIX
    float*  partial = G2 + (size_t)B*3*NPIX;        // B*NENT*RBLK

    dim3 cblk(64, 4);
    dim3 rgrd(MU/64, MU/16, B);    // residual + reduce
    dim3 g1grd(MU/128, MU/16, B);  // conv7_g1 (2 cols x 4 rows/thread)
    dim3 g2grd(MU/128, MU/8, B);   // conv7_g2 (2 cols x 2 rows/thread)

    hipLaunchKernelGGL(mlp_kernel, dim3(B), dim3(256), 0, stream,
                       kernelA, fc1_w1, fc1_b1, fc1_w2, fc1_b2,
                       fc2_w1, fc2_b1, fc2_w2, fc2_b2, w1, w2);
    hipLaunchKernelGGL(residual_kernel, rgrd, cblk, 0, stream, x, f, kernelA, r);
    hipLaunchKernelGGL(conv7_g1, g1grd, cblk, 0, stream, r, w1, G1);
    hipLaunchKernelGGL(conv7_g2, g2grd, cblk, 0, stream, G1, w2, G2);
    hipLaunchKernelGGL(reduce_kernel, rgrd, cblk, 0, stream, r, G1, G2, kernelA, partial);
    hipLaunchKernelGGL(reduce2_kernel, dim3(B), dim3(256), 0, stream, partial, Mws, bws);
    hipLaunchKernelGGL(solve_kernel, dim3((B + 63)/64), dim3(64), 0, stream, Mws, bws, Kv, B);
    hipLaunchKernelGGL(update_kernel, dim3(NPIX/1024, 1, B), dim3(256), 0, stream,
                       x, r, G1, G2, Kv, out);
}

// Round 15
// 192.123 us; speedup vs baseline: 1.4179x; 1.0150x over previous
//
#include <hip/hip_runtime.h>

#define MU 256
#define NPIX (MU*MU)
#define ML 3
#define KS 7
#define LCH 7
#define NENT 35   // 28 upper-tri M entries + 7 b entries
#define RBLK 64   // partial blocks per sample in reduce stage-1

// ---------------- MLP: per-sample dynamic kernels ----------------
__global__ void mlp_kernel(const float* __restrict__ kernelA,
                           const float* __restrict__ fc1_w1, const float* __restrict__ fc1_b1,
                           const float* __restrict__ fc1_w2, const float* __restrict__ fc1_b2,
                           const float* __restrict__ fc2_w1, const float* __restrict__ fc2_b1,
                           const float* __restrict__ fc2_w2, const float* __restrict__ fc2_b2,
                           float* __restrict__ w1_out, float* __restrict__ w2_out) {
    int b = blockIdx.x;
    int t = threadIdx.x;
    __shared__ float kA[9];
    __shared__ float h1[200], h2[200];
    if (t < 9) kA[t] = kernelA[b*9 + t];
    __syncthreads();
    if (t < 200) {
        float s1 = fc1_b1[t], s2 = fc2_b1[t];
        #pragma unroll
        for (int i = 0; i < 9; ++i) {
            s1 += kA[i] * fc1_w1[i*200 + t];
            s2 += kA[i] * fc2_w1[i*200 + t];
        }
        h1[t] = fmaxf(s1, 0.f);
        h2[t] = fmaxf(s2, 0.f);
    }
    __syncthreads();
    if (t < 147) {
        float s = fc1_b2[t];
        for (int i = 0; i < 200; ++i) s += h1[i] * fc1_w2[i*147 + t];
        w1_out[b*147 + t] = s;
    }
    for (int o = t; o < 441; o += 256) {
        float s = fc2_b2[o];
        for (int i = 0; i < 200; ++i) s += h2[i] * fc2_w2[i*441 + o];
        w2_out[b*441 + o] = s;
    }
}

// ---- FUSED: r = f - conv3x3(x) computed into LDS (incl. conv7 halo),
//      interior r written to global, then conv7x7 1->3ch from the LDS
//      r-tile (g1's proven structure: block (64,4), 2 cols x 4 rows). ----
__global__ __launch_bounds__(256) void res_g1_kernel(
        const float* __restrict__ x, const float* __restrict__ f,
        const float* __restrict__ kA, const float* __restrict__ w1,
        float* __restrict__ r, float* __restrict__ G1) {
    int b = blockIdx.z;
    __shared__ float xt[24][144];   // x: rows y0-4..y0+19, cols x0-8..x0+135
    __shared__ float rt[22][136];   // r: rows y0-3..y0+18, cols x0-4..x0+131
    int tx = threadIdx.x;
    int ty = threadIdx.y;
    int tid = ty*64 + tx;
    int x0 = blockIdx.x*128, y0 = blockIdx.y*16;
    const float* xb = x + (size_t)b*NPIX;
    const float* fb = f + (size_t)b*NPIX;
    const float* wgt = w1 + (size_t)b*147;   // uniform -> SGPR loads
    float k[9];
    #pragma unroll
    for (int i = 0; i < 9; ++i) k[i] = kA[b*9 + i];

    // stage x-tile (float4 chunks; fully in/out since MU%4==0)
    for (int u = tid; u < 24*36; u += 256) {
        int row = u / 36, q4 = u % 36;
        int yy = y0 + row - 4;
        int xx = x0 - 8 + q4*4;
        float4 vv = make_float4(0.f, 0.f, 0.f, 0.f);
        if (yy >= 0 && yy < MU && xx >= 0 && xx < MU)
            vv = *(const float4*)(xb + yy*MU + xx);
        *(float4*)&xt[row][q4*4] = vv;
    }
    __syncthreads();

    // compute r-tile: rt[row][col] for image (y0-3+row, x0-4+col)
    for (int u = tid; u < 22*34; u += 256) {
        int row = u / 34, c4 = u % 34;
        int Y = y0 - 3 + row;
        int X = x0 - 4 + 4*c4;
        bool inb = (Y >= 0 && Y < MU && X >= 0 && X < MU);
        float4 fv = make_float4(0.f, 0.f, 0.f, 0.f);
        if (inb) fv = *(const float4*)(fb + Y*MU + X);
        float fr[4] = {fv.x, fv.y, fv.z, fv.w};
        float rr[4];
        #pragma unroll
        for (int cc = 0; cc < 4; ++cc) {
            float s = 0.f;
            #pragma unroll
            for (int di = 0; di < 3; ++di)
                #pragma unroll
                for (int dj = 0; dj < 3; ++dj)
                    s += xt[row + di][4*c4 + 3 + cc + dj] * k[di*3 + dj];
            rr[cc] = inb ? (fr[cc] - s) : 0.f;
        }
        *(float4*)&rt[row][4*c4] = make_float4(rr[0], rr[1], rr[2], rr[3]);
    }
    __syncthreads();

    // conv7 (identical to proven g1), + write interior r to global
    float accA[3][4], accB[3][4];
    #pragma unroll
    for (int co = 0; co < 3; ++co)
        #pragma unroll
        for (int dy = 0; dy < 4; ++dy) { accA[co][dy] = 0.f; accB[co][dy] = 0.f; }

    int ry = ty*4;
    #pragma unroll
    for (int ir = 0; ir < 10; ++ir) {
        float v[10];
        #pragma unroll
        for (int h = 0; h < 5; ++h)
            *(float2*)&v[h*2] = *(float2*)&rt[ry + ir][2*tx + h*2];
        #pragma unroll
        for (int dy = 0; dy < 4; ++dy) {
            int i = ir - dy;
            if (i >= 0 && i <= 6) {
                #pragma unroll
                for (int co = 0; co < 3; ++co)
                    #pragma unroll
                    for (int j = 0; j < 7; ++j) {
                        float w = wgt[(co*7 + i)*7 + j];
                        accA[co][dy] += v[1 + j] * w;
                        accB[co][dy] += v[2 + j] * w;
                    }
            }
        }
    }
    #pragma unroll
    for (int dy = 0; dy < 4; ++dy) {
        size_t pr = (size_t)b*NPIX + (size_t)(y0 + ry + dy)*MU + x0 + 2*tx;
        *(float2*)&r[pr] = *(float2*)&rt[3 + ry + dy][4 + 2*tx];
        size_t p = (size_t)b*3*NPIX + (size_t)(y0 + ry + dy)*MU + x0 + 2*tx;
        #pragma unroll
        for (int co = 0; co < 3; ++co)
            *(float2*)&G1[p + (size_t)co*NPIX] = make_float2(accA[co][dy], accB[co][dy]);
    }
}

// ---- conv7x7 3->3ch. R9 configuration (best measured: 61 us):
//      tile[3][14][136] = 22.8 KB, block (64,4), 2 cols x 2 rows/thread. ----
__global__ __launch_bounds__(256) void conv7_g2(
        const float* __restrict__ G1, const float* __restrict__ w2,
        float* __restrict__ G2) {
    int b = blockIdx.z;
    __shared__ float tile[3][14][136];
    int tx = threadIdx.x;
    int ty = threadIdx.y;
    int tid = ty*64 + tx;
    int x0 = blockIdx.x*128, y0 = blockIdx.y*8;
    const float* g1b = G1 + (size_t)b*3*NPIX;
    const float* wgt = w2 + (size_t)b*441;

    for (int u = tid; u < 3*14*34; u += 256) {
        int c = u / (14*34);
        int rem = u % (14*34);
        int row = rem / 34, q4 = rem % 34;
        int yy = y0 + row - 3;
        int xx = x0 - 4 + q4*4;
        float4 vv = make_float4(0.f, 0.f, 0.f, 0.f);
        if (yy >= 0 && yy < MU && xx >= 0 && xx < MU)
            vv = *(const float4*)(g1b + (size_t)c*NPIX + yy*MU + xx);
        *(float4*)&tile[c][row][q4*4] = vv;
    }
    __syncthreads();

    float accA[3][2], accB[3][2];
    #pragma unroll
    for (int co = 0; co < 3; ++co)
        #pragma unroll
        for (int dy = 0; dy < 2; ++dy) { accA[co][dy] = 0.f; accB[co][dy] = 0.f; }

    int ry = ty*2;
    #pragma unroll
    for (int c = 0; c < 3; ++c) {
        #pragma unroll
        for (int ir = 0; ir < 8; ++ir) {
            float v[10];
            #pragma unroll
            for (int h = 0; h < 5; ++h)
                *(float2*)&v[h*2] = *(float2*)&tile[c][ry + ir][2*tx + h*2];
            #pragma unroll
            for (int dy = 0; dy < 2; ++dy) {
                int i = ir - dy;
                if (i >= 0 && i <= 6) {
                    #pragma unroll
                    for (int co = 0; co < 3; ++co)
                        #pragma unroll
                        for (int j = 0; j < 7; ++j) {
                            float w = wgt[((co*3 + c)*7 + i)*7 + j];
                            accA[co][dy] += v[1 + j] * w;
                            accB[co][dy] += v[2 + j] * w;
                        }
                }
            }
        }
    }
    #pragma unroll
    for (int dy = 0; dy < 2; ++dy) {
        size_t p = (size_t)b*3*NPIX + (size_t)(y0 + ry + dy)*MU + x0 + 2*tx;
        #pragma unroll
        for (int co = 0; co < 3; ++co)
            *(float2*)&G2[p + (size_t)co*NPIX] = make_float2(accA[co][dy], accB[co][dy]);
    }
}

// ---- S = depthwise3x3(G, kernelA); stage-1 Gram partials.
//      Butterfly SPLIT-reduction: 63 shfl total (vs 35x6=210). ----
__global__ __launch_bounds__(256, 4) void reduce_kernel(
        const float* __restrict__ r, const float* __restrict__ G1,
        const float* __restrict__ G2, const float* __restrict__ kA,
        float* __restrict__ partial) {
    int b = blockIdx.z;
    __shared__ float tile[7][18][72];
    __shared__ float wsum[NENT][4];
    int tx = threadIdx.x;          // 0..63 = lane; wave == one ty
    int ty = threadIdx.y;          // 0..3
    int tid = ty*64 + tx;
    float k[9];
    #pragma unroll
    for (int i = 0; i < 9; ++i) k[i] = kA[b*9 + i];

    const float* srcs[7] = {
        r  + (size_t)b*NPIX,
        G1 + (size_t)b*3*NPIX, G1 + (size_t)b*3*NPIX + NPIX, G1 + (size_t)b*3*NPIX + 2*NPIX,
        G2 + (size_t)b*3*NPIX, G2 + (size_t)b*3*NPIX + NPIX, G2 + (size_t)b*3*NPIX + 2*NPIX
    };

    int x0 = blockIdx.x*64;
    int ysub = blockIdx.y*16;

    #pragma unroll
    for (int c = 0; c < 7; ++c) {
        const float* src = srcs[c];
        for (int u = tid; u < 18*18; u += 256) {
            int row = u / 18, q4 = u % 18;
            int yy = ysub + row - 1;
            int xx = x0 - 4 + q4*4;
            float4 vv = make_float4(0.f, 0.f, 0.f, 0.f);
            if (yy >= 0 && yy < MU && xx >= 0 && xx < MU)
                vv = *(const float4*)(src + yy*MU + xx);
            *(float4*)&tile[c][row][q4*4] = vv;
        }
    }
    __syncthreads();

    float acc[64];
    #pragma unroll
    for (int e = 0; e < 64; ++e) acc[e] = 0.f;

    int ry = ty*4;
    float S_all[7][4];
    #pragma unroll
    for (int c = 0; c < 7; ++c) {
        float S0 = 0.f, S1 = 0.f, S2 = 0.f, S3 = 0.f;
        #pragma unroll
        for (int t = 0; t < 6; ++t) {
            float v0 = tile[c][ry + t][tx + 3];
            float v1 = tile[c][ry + t][tx + 4];
            float v2 = tile[c][ry + t][tx + 5];
            float e0 = v0*k[0] + v1*k[1] + v2*k[2];
            float e1 = v0*k[3] + v1*k[4] + v2*k[5];
            float e2 = v0*k[6] + v1*k[7] + v2*k[8];
            if (t == 0) { S0 += e0; }
            if (t == 1) { S1 += e0; S0 += e1; }
            if (t == 2) { S2 += e0; S1 += e1; S0 += e2; }
            if (t == 3) { S3 += e0; S2 += e1; S1 += e2; }
            if (t == 4) {           S3 += e1; S2 += e2; }
            if (t == 5) {                     S3 += e2; }
        }
        S_all[c][0] = S0; S_all[c][1] = S1; S_all[c][2] = S2; S_all[c][3] = S3;
    }
    #pragma unroll
    for (int dy = 0; dy < 4; ++dy) {
        float rv = tile[0][ry + dy + 1][tx + 4];
        int idx = 0;
        #pragma unroll
        for (int l = 0; l < 7; ++l) {
            #pragma unroll
            for (int m = l; m < 7; ++m) {
                acc[idx] += S_all[l][dy] * S_all[m][dy];
                ++idx;
            }
        }
        #pragma unroll
        for (int l = 0; l < 7; ++l) acc[28 + l] += S_all[l][dy] * rv;
    }

    // butterfly split-reduce: lane ends holding full sum of entry bitrev6(lane)
    #pragma unroll
    for (int step = 0; step < 6; ++step) {
        const int mask = 1 << step;
        const int nh = 32 >> step;
        bool hi = (tx & mask) != 0;
        #pragma unroll
        for (int i = 0; i < nh; ++i) {
            float send = hi ? acc[i] : acc[i + nh];
            float got = __shfl_xor(send, mask);
            acc[i] = (hi ? acc[i + nh] : acc[i]) + got;
        }
    }
    int ent = ((tx&1)<<5) | ((tx&2)<<3) | ((tx&4)<<1)
            | ((tx&8)>>1) | ((tx&16)>>3) | ((tx&32)>>5);
    if (ent < NENT) wsum[ent][ty] = acc[0];
    __syncthreads();
    if (tid < NENT) {
        float s = wsum[tid][0] + wsum[tid][1] + wsum[tid][2] + wsum[tid][3];
        int blockLinear = blockIdx.y*4 + blockIdx.x;   // 0..63
        partial[((size_t)b*NENT + tid)*RBLK + blockLinear] = s;
    }
}

// ---- stage-2: sum RBLK per-block partials per (sample, entry) in f64 ----
__global__ void reduce2_kernel(const float* __restrict__ partial,
                               double* __restrict__ M, double* __restrict__ bv) {
    int b = blockIdx.x;
    int wave = threadIdx.x >> 6;
    int lane = threadIdx.x & 63;
    for (int e = wave; e < NENT; e += 4) {
        const float* p = partial + ((size_t)b*NENT + e)*RBLK;
        double s = (double)p[lane];
        #pragma unroll
        for (int off = 32; off; off >>= 1) s += __shfl_down(s, off);
        if (lane == 0) {
            if (e < 28) M[b*28 + e] = s;
            else        bv[b*7 + (e - 28)] = s;
        }
    }
}

// ---- per-sample 7x7 solve: f64, partial pivoting, ALL-STATIC indexing ----
__global__ __launch_bounds__(64, 1) void solve_kernel(
        const double* __restrict__ M, const double* __restrict__ bv,
        float* __restrict__ K, int B) {
    int b = blockIdx.x*64 + threadIdx.x;
    if (b >= B) return;
    double A[7][8];
    int idx = 0;
    #pragma unroll
    for (int l = 0; l < 7; ++l)
        #pragma unroll
        for (int m = l; m < 7; ++m) {
            double v = M[b*28 + idx];
            A[l][m] = v;
            A[m][l] = v;
            ++idx;
        }
    #pragma unroll
    for (int l = 0; l < 7; ++l) A[l][7] = bv[b*7 + l];

    #pragma unroll
    for (int col = 0; col < 7; ++col) {
        int piv = col;
        double mx = fabs(A[col][col]);
        #pragma unroll
        for (int rr = 0; rr < 7; ++rr) {
            if (rr > col) {
                double a = fabs(A[rr][col]);
                if (a > mx) { mx = a; piv = rr; }
            }
        }
        #pragma unroll
        for (int rr = 0; rr < 7; ++rr) {
            if (rr > col) {
                bool c = (rr == piv);
                #pragma unroll
                for (int cc = 0; cc < 8; ++cc) {
                    double t0 = A[col][cc], t1 = A[rr][cc];
                    A[col][cc] = c ? t1 : t0;
                    A[rr][cc]  = c ? t0 : t1;
                }
            }
        }
        double d = A[col][col];
        #pragma unroll
        for (int rr = 0; rr < 7; ++rr) {
            if (rr > col) {
                double fct = A[rr][col] / d;
                #pragma unroll
                for (int cc = 0; cc < 8; ++cc) A[rr][cc] -= fct * A[col][cc];
            }
        }
    }
    double Kv[7];
    #pragma unroll
    for (int rr = 6; rr >= 0; --rr) {
        double s = A[rr][7];
        #pragma unroll
        for (int cc = 0; cc < 7; ++cc)
            if (cc > rr) s -= A[rr][cc] * Kv[cc];
        Kv[rr] = s / A[rr][rr];
    }
    #pragma unroll
    for (int l = 0; l < 7; ++l) K[b*7 + l] = (float)Kv[l];
}

// ---------------- x_new = x + K^T G (float4-vectorized) ----------------
__global__ void update_kernel(const float* __restrict__ x, const float* __restrict__ r,
                              const float* __restrict__ G1, const float* __restrict__ G2,
                              const float* __restrict__ K, float* __restrict__ out) {
    int b = blockIdx.z;
    int p4 = blockIdx.x*256 + threadIdx.x;
    float k0 = K[b*7+0], k1 = K[b*7+1], k2 = K[b*7+2], k3 = K[b*7+3];
    float k4 = K[b*7+4], k5 = K[b*7+5], k6 = K[b*7+6];
    size_t q  = (size_t)b*(NPIX/4) + p4;
    size_t q3 = (size_t)b*3*(NPIX/4) + p4;
    const float4* x4  = (const float4*)x;
    const float4* r4  = (const float4*)r;
    const float4* g14 = (const float4*)G1;
    const float4* g24 = (const float4*)G2;
    float4 xv = x4[q], rv = r4[q];
    float4 a = g14[q3], bb = g14[q3 + NPIX/4], c = g14[q3 + 2*(NPIX/4)];
    float4 d = g24[q3], e  = g24[q3 + NPIX/4], g = g24[q3 + 2*(NPIX/4)];
    float4 o;
    o.x = xv.x + k0*rv.x + k1*a.x + k2*bb.x + k3*c.x + k4*d.x + k5*e.x + k6*g.x;
    o.y = xv.y + k0*rv.y + k1*a.y + k2*bb.y + k3*c.y + k4*d.y + k5*e.y + k6*g.y;
    o.z = xv.z + k0*rv.z + k1*a.z + k2*bb.z + k3*c.z + k4*d.z + k5*e.z + k6*g.z;
    o.w = xv.w + k0*rv.w + k1*a.w + k2*bb.w + k3*c.w + k4*d.w + k5*e.w + k6*g.w;
    ((float4*)out)[q] = o;
}

extern "C" void kernel_launch(void* const* d_in, const int* in_sizes, int n_in,
                              void* d_out, int out_size, void* d_ws, size_t ws_size,
                              hipStream_t stream) {
    const float* x       = (const float*)d_in[0];
    const float* f       = (const float*)d_in[1];
    const float* kernelA = (const float*)d_in[2];
    const float* fc1_w1  = (const float*)d_in[3];
    const float* fc1_b1  = (const float*)d_in[4];
    const float* fc1_w2  = (const float*)d_in[5];
    const float* fc1_b2  = (const float*)d_in[6];
    const float* fc2_w1  = (const float*)d_in[7];
    const float* fc2_b1  = (const float*)d_in[8];
    const float* fc2_w2  = (const float*)d_in[9];
    const float* fc2_b2  = (const float*)d_in[10];
    float* out = (float*)d_out;

    const int B = in_sizes[2] / 9;

    // workspace layout (doubles first for 8B alignment; no +1 after Kv —
    // keeps r/G1/G2/partial 16B-aligned for float4 loads).
    double* Mws = (double*)d_ws;                    // B*28
    double* bws = Mws + (size_t)B*28;               // B*7
    float*  w1  = (float*)(bws + (size_t)B*7);      // B*147
    float*  w2  = w1 + (size_t)B*147;               // B*441
    float*  Kv  = w2 + (size_t)B*441;               // B*7
    float*  r   = Kv + (size_t)B*7;                 // B*NPIX (16B-aligned)
    float*  G1  = r  + (size_t)B*NPIX;              // B*3*NPIX
    float*  G2  = G1 + (size_t)B*3*NPIX;            // B*3*NPIX
    float*  partial = G2 + (size_t)B*3*NPIX;        // B*NENT*RBLK

    dim3 cblk(64, 4);
    dim3 rgrd(MU/64, MU/16, B);    // reduce
    dim3 g1grd(MU/128, MU/16, B);  // res_g1 (2 cols x 4 rows/thread)
    dim3 g2grd(MU/128, MU/8, B);   // conv7_g2 (2 cols x 2 rows/thread)

    hipLaunchKernelGGL(mlp_kernel, dim3(B), dim3(256), 0, stream,
                       kernelA, fc1_w1, fc1_b1, fc1_w2, fc1_b2,
                       fc2_w1, fc2_b1, fc2_w2, fc2_b2, w1, w2);
    hipLaunchKernelGGL(res_g1_kernel, g1grd, cblk, 0, stream, x, f, kernelA, w1, r, G1);
    hipLaunchKernelGGL(conv7_g2, g2grd, cblk, 0, stream, G1, w2, G2);
    hipLaunchKernelGGL(reduce_kernel, rgrd, cblk, 0, stream, r, G1, G2, kernelA, partial);
    hipLaunchKernelGGL(reduce2_kernel, dim3(B), dim3(256), 0, stream, partial, Mws, bws);
    hipLaunchKernelGGL(solve_kernel, dim3((B + 63)/64), dim3(64), 0, stream, Mws, bws, Kv, B);
    hipLaunchKernelGGL(update_kernel, dim3(NPIX/1024, 1, B), dim3(256), 0, stream,
                       x, r, G1, G2, Kv, out);
}